// Round 5
// baseline (262.723 us; speedup 1.0000x reference)
//
#include <hip/hip_runtime.h>

#define CIN 64
#define COUT 64
#define BATCH 32
#define KTOT 576            // CIN * 9
#define NPOS 1024

// halo-padded transposed input: xT[i][34][34][b]
__device__ float g_xT[CIN * 34 * 34 * BATCH];

// Coalesced transpose repack: one block per (i, hh). Reads x rows (lanes over
// w, 128 B segments), transposes through LDS, writes g_xT rows (lanes over b,
// 128 B segments). Halo rows/cols written as zeros.
__global__ __launch_bounds__(256) void repack_kernel(const float* __restrict__ x) {
    __shared__ float tile[32 * 33];        // [b][w], pad 33 -> conflict-free
    const int i   = blockIdx.x;            // 0..63
    const int hh  = blockIdx.y;            // 0..33
    const int tid = threadIdx.x;

    float* dst = &g_xT[((i * 34 + hh) * 34) * BATCH];

    if (hh == 0 || hh == 33) {             // halo row: all zeros (34*32 floats)
        for (int idx = tid; idx < 34 * BATCH; idx += 256) dst[idx] = 0.f;
        return;
    }
    const int hs = hh - 1;
#pragma unroll
    for (int bb = 0; bb < 4; ++bb) {       // read 8 b-rows per pass
        int b = bb * 8 + (tid >> 5);
        int w = tid & 31;
        tile[b * 33 + w] = x[(b << 16) + (i << 10) + (hs << 5) + w];
    }
    __syncthreads();
#pragma unroll
    for (int q = 0; q < 5; ++q) {          // write 8 ww-rows per pass (34 total)
        int ww = q * 8 + (tid >> 5);
        if (ww < 34) {
            int b = tid & 31;
            float v = (ww == 0 || ww == 33) ? 0.f : tile[b * 33 + (ww - 1)];
            dst[ww * BATCH + b] = v;
        }
    }
}

// Block = (position p, cout-half oh), grid 2048. 512 threads = 8 waves.
// W half-panel [32 o][576 k] resident in LDS (72 KB -> 2 blocks/CU = 4
// waves/SIMD). P fragments read straight from L2 (g_xT slice is ~3.3 MB/XCD).
// 8-way K-split across waves (72 k each), LDS reduction at the end.
//
// No global_load_lds anywhere: rounds 0-4 showed scattered-source LDS-DMA
// serializes at ~200+ cyc/instr per CU and pins the kernel at ~91 us.
//
// W LDS image: granule g = kq*32 + o  (granule = 4 floats = W[o][4kq..4kq+4)).
//   stage:  thread t, pass q: dest granule q*512+t (linear ds_write_b128,
//           conflict-free); source = row (t&31), k-granule q*16+(t>>5)
//           (per-thread base + q*256 B -> offset-folded loads).
//   read:   (kq, oc) -> granules kq*32 + oc*8 + og2: 8 og2-lanes consecutive
//           granules = 128 B across all banks -> conflict-free; bg lanes
//           duplicate -> broadcast. All offsets compile-time immediates.
__global__ __launch_bounds__(512, 4) void local2d_kernel(
    const float* __restrict__ weight,
    const float* __restrict__ bias,
    float* __restrict__ out)
{
    __shared__ __align__(16) float lds[144 * 32 * 4];   // 73728 B

    const int tid = threadIdx.x;
    const int wv  = tid >> 6;              // wave 0..7  (K-band)
    const int l   = tid & 63;
    const int bg  = l & 7;                 // b-group: b = bg*4 + bb
    const int og2 = l >> 3;                // o-sub:   o = oc*8 + og2

    // row-granular XCD swizzle (r4's proven mapping): xcd owns whole output
    // rows; the two oh-halves of a position are dispatch-adjacent.
    int bid = blockIdx.x;
    int xcd = bid & 7;
    int t   = bid >> 3;                    // 0..255
    int oh  = t & 1;                       // cout half
    int tt  = t >> 1;                      // 0..127
    int y   = ((tt >> 5) << 3) | xcd;
    int xw  = tt & 31;
    int p   = (y << 5) | xw;               // position

    // ---- stage W half-panel: 32 rows x 576 k = 73728 B ----
    {
        const float* src = weight + ((long)p * COUT + (oh << 5)) * KTOT
                         + (tid & 31) * KTOT + ((tid >> 5) << 2);
#pragma unroll
        for (int q = 0; q < 9; ++q) {
            *(float4*)(&lds[((q << 9) + tid) << 2]) =
                *(const float4*)(src + (q << 6));
        }
    }
    __syncthreads();

    float acc[4][4];
#pragma unroll
    for (int a = 0; a < 4; ++a)
#pragma unroll
        for (int c = 0; c < 4; ++c) acc[a][c] = 0.f;

    // wave-level bases (runtime, computed once)
    const float* pb = g_xT + (((wv << 3) * 1156 + y * 34 + xw) << 5) + (bg << 2);
    const float* wb = &lds[(wv * 2304) + (og2 << 2)];   // wv*18 granule rows

    // k = wv*72 + 4g + j ; i = wv*8 + di, with (4g+j) = di*9 + kh*3 + kw
#pragma unroll
    for (int g = 0; g < 18; ++g) {
        float4 pr[4];
#pragma unroll
        for (int j = 0; j < 4; ++j) {
            const int c  = 4 * g + j;      // 0..71 (compile-time)
            const int di = c / 9;
            const int rr = c - 9 * di;
            const int kh = rr / 3;
            const int kw = rr - 3 * kh;
            pr[j] = *(const float4*)(pb + ((di * 1156 + kh * 34 + kw) << 5));
        }
        const float* prf = (const float*)pr;
#pragma unroll
        for (int oc = 0; oc < 4; ++oc) {
            // granule (kq = wv*18 + g, o = oc*8 + og2); static offset g*128+oc*32
            float4 wr = *(const float4*)(wb + (g << 7) + (oc << 5));
#pragma unroll
            for (int bb = 0; bb < 4; ++bb) {
                float a = acc[oc][bb];
                a = fmaf(wr.x, prf[0 * 4 + bb], a);
                a = fmaf(wr.y, prf[1 * 4 + bb], a);
                a = fmaf(wr.z, prf[2 * 4 + bb], a);
                a = fmaf(wr.w, prf[3 * 4 + bb], a);
                acc[oc][bb] = a;
            }
        }
    }

    // ---- 8-way cross-wave reduction (reuse W region; 7 slots x 32x36) ----
    __syncthreads();                       // all waves done reading W
    if (wv != 0) {
        float* R = &lds[(wv - 1) * 1152];  // stride 36 floats: 16B-aligned,
#pragma unroll                             // og2 bank-stride 4 -> conflict-free
        for (int oc = 0; oc < 4; ++oc) {
            int o = (oc << 3) + og2;
            *(float4*)(&R[o * 36 + (bg << 2)]) =
                make_float4(acc[oc][0], acc[oc][1], acc[oc][2], acc[oc][3]);
        }
    }
    __syncthreads();
    if (wv == 0) {
#pragma unroll
        for (int oc = 0; oc < 4; ++oc) {
            int o  = (oc << 3) + og2;
            int of = (oh << 5) + o;        // global cout
            float s0 = acc[oc][0], s1 = acc[oc][1], s2 = acc[oc][2], s3 = acc[oc][3];
#pragma unroll
            for (int s = 0; s < 7; ++s) {
                float4 r = *(const float4*)(&lds[s * 1152 + o * 36 + (bg << 2)]);
                s0 += r.x; s1 += r.y; s2 += r.z; s3 += r.w;
            }
            float bv = bias[(of << 10) + p];
            int b0 = bg << 2;
            out[((b0 + 0) << 16) + (of << 10) + p] = s0 + bv;
            out[((b0 + 1) << 16) + (of << 10) + p] = s1 + bv;
            out[((b0 + 2) << 16) + (of << 10) + p] = s2 + bv;
            out[((b0 + 3) << 16) + (of << 10) + p] = s3 + bv;
        }
    }
}

extern "C" void kernel_launch(void* const* d_in, const int* in_sizes, int n_in,
                              void* d_out, int out_size, void* d_ws, size_t ws_size,
                              hipStream_t stream) {
    const float* x      = (const float*)d_in[0];
    const float* weight = (const float*)d_in[1];
    const float* bias   = (const float*)d_in[2];
    float* out          = (float*)d_out;

    hipLaunchKernelGGL(repack_kernel, dim3(CIN, 34), dim3(256), 0, stream, x);
    hipLaunchKernelGGL(local2d_kernel, dim3(2 * NPOS), dim3(512), 0, stream,
                       weight, bias, out);
}